// Round 6
// baseline (1869.732 us; speedup 1.0000x reference)
//
#include <hip/hip_runtime.h>
#include <hip/hip_bf16.h>
#include <stdint.h>

// GraphSAGE layer, N=16384, F_IN=F_OUT=256.
// out = (adj@ (x@W1))/deg + x@W2 + bias
//   K0: WT[n][k] (bf16)  = transpose of [W1|W2]
//   K1: yTt[j/32][n][32] (bf16, K-TILED) = (x@W1)^T ; z[m][n] = x@W2 + bias
//   K2 v12 (REAL, unchanged): v9 convoy structure + nt hints + ky-per-XCD.
//   K3: out = (p0+p1)/(d0+d1) + z
//   K2X (MEASUREMENT, scratch output): A-direct-to-register variant.
//       Appended after the real pipeline; writes only scratch at ws+64MB.
//       T(K2X) = total_dur - 1425.2 (v12's measured total) -> exact
//       within-probe duration of the new structure.

typedef short bf16x8 __attribute__((ext_vector_type(8)));
typedef float f32x4  __attribute__((ext_vector_type(4)));
typedef int   i32x4  __attribute__((ext_vector_type(4)));

__device__ __forceinline__ uint32_t pack_bf16_rne(float lo, float hi) {
    uint32_t ul = __float_as_uint(lo);
    uint32_t uh = __float_as_uint(hi);
    ul = (ul + 0x7fffu + ((ul >> 16) & 1u)) >> 16;
    uh = (uh + 0x7fffu + ((uh >> 16) & 1u)) >> 16;
    return ul | (uh << 16);
}

__device__ __forceinline__ void gld_lds16(const uint16_t* g, uint16_t* l) {
    __builtin_amdgcn_global_load_lds(
        (const __attribute__((address_space(1))) void*)g,
        (__attribute__((address_space(3))) void*)l, 16, 0, 0);
}

// ---------------- K0: transpose weight [512,256] f32 -> WT [512(n)][256(k)] bf16
__global__ __launch_bounds__(256) void k_transpose_w(const float* __restrict__ w,
                                                     uint16_t* __restrict__ wt) {
    int idx = blockIdx.x * 256 + threadIdx.x;   // 0..131071
    int n = idx >> 8;
    int k = idx & 255;
    int row = (n < 256) ? k : (256 + k);
    int col = (n < 256) ? n : (n - 256);
    uint32_t u = __float_as_uint(w[row * 256 + col]);
    u = (u + 0x7fffu + ((u >> 16) & 1u)) >> 16;
    wt[idx] = (uint16_t)u;
}

// ---------------- K1: small GEMM  [16384,256] @ [256,512]
__global__ __launch_bounds__(256) void k_small_gemm(const float* __restrict__ x,
                                                    const uint16_t* __restrict__ wt,
                                                    const float* __restrict__ bias,
                                                    uint16_t* __restrict__ yTt,
                                                    float* __restrict__ z) {
    __shared__ uint16_t As[128 * 32];  // [m][k] bf16
    __shared__ uint16_t Bs[128 * 32];  // [n][k] bf16

    const int t  = threadIdx.x;
    const int ct = blockIdx.x;        // 0..3
    const int rt = blockIdx.y;        // 0..127
    const int m0 = rt * 128;
    const int n0 = ct * 128;

    const int lane = t & 63, w = t >> 6;
    const int wr = w >> 1, wc = w & 1;
    const int l15 = lane & 15, quad = lane >> 4;

    f32x4 acc[4][4] = {};

    float4 a_reg[4];
    uint4  b_reg[2];

#pragma unroll
    for (int i = 0; i < 4; ++i) {
        int f4 = t + 256 * i, row = f4 >> 3, c4 = f4 & 7;
        a_reg[i] = *(const float4*)(x + (m0 + row) * 256 + c4 * 4);
    }
#pragma unroll
    for (int i = 0; i < 2; ++i) {
        int u4 = t + 256 * i, n_l = u4 >> 2, part = u4 & 3;
        b_reg[i] = *(const uint4*)(wt + (n0 + n_l) * 256 + part * 8);
    }

    for (int kk = 0; kk < 8; ++kk) {
        __syncthreads();
#pragma unroll
        for (int i = 0; i < 4; ++i) {
            int f4 = t + 256 * i, row = f4 >> 3, c4 = f4 & 7;
            uint2 p;
            p.x = pack_bf16_rne(a_reg[i].x, a_reg[i].y);
            p.y = pack_bf16_rne(a_reg[i].z, a_reg[i].w);
            *(uint2*)(As + row * 32 + c4 * 4) = p;
        }
#pragma unroll
        for (int i = 0; i < 2; ++i) {
            int u4 = t + 256 * i, n_l = u4 >> 2, part = u4 & 3;
            *(uint4*)(Bs + n_l * 32 + part * 8) = b_reg[i];
        }
        if (kk < 7) {
            int k0 = (kk + 1) * 32;
#pragma unroll
            for (int i = 0; i < 4; ++i) {
                int f4 = t + 256 * i, row = f4 >> 3, c4 = f4 & 7;
                a_reg[i] = *(const float4*)(x + (m0 + row) * 256 + k0 + c4 * 4);
            }
#pragma unroll
            for (int i = 0; i < 2; ++i) {
                int u4 = t + 256 * i, n_l = u4 >> 2, part = u4 & 3;
                b_reg[i] = *(const uint4*)(wt + (n0 + n_l) * 256 + k0 + part * 8);
            }
        }
        __syncthreads();

        bf16x8 a_frag[4], b_frag[4];
#pragma unroll
        for (int fr = 0; fr < 4; ++fr)
            a_frag[fr] = *(const bf16x8*)(As + (wr * 64 + fr * 16 + l15) * 32 + quad * 8);
#pragma unroll
        for (int fc = 0; fc < 4; ++fc)
            b_frag[fc] = *(const bf16x8*)(Bs + (wc * 64 + fc * 16 + l15) * 32 + quad * 8);
#pragma unroll
        for (int fr = 0; fr < 4; ++fr)
#pragma unroll
            for (int fc = 0; fc < 4; ++fc)
                acc[fr][fc] = __builtin_amdgcn_mfma_f32_16x16x32_bf16(
                    a_frag[fr], b_frag[fc], acc[fr][fc], 0, 0, 0);
    }

    if (ct < 2) {
#pragma unroll
        for (int fr = 0; fr < 4; ++fr) {
            int m_base = m0 + wr * 64 + fr * 16 + quad * 4;
#pragma unroll
            for (int fc = 0; fc < 4; ++fc) {
                int n_g = n0 + wc * 64 + fc * 16 + l15;   // 0..255
                uint2 pp;
                pp.x = pack_bf16_rne(acc[fr][fc][0], acc[fr][fc][1]);
                pp.y = pack_bf16_rne(acc[fr][fc][2], acc[fr][fc][3]);
                *(uint2*)(yTt + (size_t)(m_base >> 5) * 8192 + n_g * 32 + (m_base & 31)) = pp;
            }
        }
    } else {
#pragma unroll
        for (int fr = 0; fr < 4; ++fr) {
            int m_base = m0 + wr * 64 + fr * 16 + quad * 4;
#pragma unroll
            for (int fc = 0; fc < 4; ++fc) {
                int n_g = (n0 - 256) + wc * 64 + fc * 16 + l15;  // 0..255
                float bv = bias[n_g];
#pragma unroll
                for (int r = 0; r < 4; ++r)
                    z[(size_t)(m_base + r) * 256 + n_g] = acc[fr][fc][r] + bv;
            }
        }
    }
}

// ---------------- K2 v12 (REAL — unchanged from the 1425.2 us run)
#define A_STRIDE 36
#define B_STRIDE 36
#define A_SZ (64 * A_STRIDE)
#define B_SZ (256 * B_STRIDE)
#define KITER 256

#define STEP(ARD, BRD, AWR, BWR, KK)                                            \
  do {                                                                          \
    if ((KK) < KITER - 2) {                                                     \
      bN0 = *(const uint4*)(pB);                                                \
      bN1 = *(const uint4*)(pB + 4096);                                         \
      pB += 8192;                                                               \
    }                                                                           \
    if ((KK) < KITER - 4) {                                                     \
      aN = __builtin_nontemporal_load(pa4); pa4 += 8;                           \
    }                                                                           \
    if ((KK) < KITER - 1) {                                                     \
      degp += q1.x + q1.y + q1.z + q1.w;                                        \
      uint2 pv;                                                                 \
      pv.x = (uint32_t)(q1.x | (q1.y << 16)) * 0x3F80u;                         \
      pv.y = (uint32_t)(q1.z | (q1.w << 16)) * 0x3F80u;                         \
      *(uint2*)&As##AWR[a_lds] = pv;                                            \
      *(uint4*)&Bs##BWR[b_lds0] = bC0;                                          \
      *(uint4*)&Bs##BWR[b_lds1] = bC1;                                          \
    }                                                                           \
    {                                                                           \
      bf16x8 af[2], bfr[4];                                                     \
      _Pragma("unroll") for (int fr = 0; fr < 2; ++fr) {                        \
        int row = wr * 32 + fr * 16 + l15;                                      \
        af[fr] = *(const bf16x8*)(As##ARD + row * A_STRIDE + quad * 8);         \
      }                                                                         \
      _Pragma("unroll") for (int fc = 0; fc < 4; ++fc) {                        \
        int n = wc * 64 + fc * 16 + l15;                                        \
        bfr[fc] = *(const bf16x8*)(Bs##BRD + n * B_STRIDE + quad * 8);          \
      }                                                                         \
      _Pragma("unroll") for (int fr = 0; fr < 2; ++fr)                          \
        _Pragma("unroll") for (int fc = 0; fc < 4; ++fc)                        \
          acc[fr][fc] = __builtin_amdgcn_mfma_f32_16x16x32_bf16(                \
              af[fr], bfr[fc], acc[fr][fc], 0, 0, 0);                           \
    }                                                                           \
    q1 = q2; q2 = q3; q3 = aN;                                                  \
    bC0 = bN0; bC1 = bN1;                                                       \
    asm volatile("s_waitcnt lgkmcnt(0)\n\ts_barrier" ::: "memory");             \
  } while (0)

__global__ __launch_bounds__(512, 4) void k_big_gemm(const int* __restrict__ adj,
                                                     const uint16_t* __restrict__ yTt,
                                                     float* __restrict__ part,
                                                     int* __restrict__ degw) {
    __shared__ uint16_t As0[A_SZ], As1[A_SZ], As2[A_SZ];
    __shared__ uint16_t Bs0[B_SZ], Bs1[B_SZ], Bs2[B_SZ];

    const int t = threadIdx.x;
    const int id   = blockIdx.x + (int)gridDim.x * blockIdx.y;  // 0..511
    const int xcd  = id & 7, slot = id >> 3;
    const int ky   = xcd >> 2;
    const int m0   = ((xcd & 3) * 64 + slot) * 64;
    const int lane = t & 63, w = t >> 6;
    const int wr = w >> 2, wc = w & 3;
    const int l15 = lane & 15, quad = lane >> 4;

    f32x4 acc[2][4] = {};

    const int a_n = t >> 3, a_c4 = t & 7;
    const i32x4* pa4 = (const i32x4*)(adj + (size_t)(m0 + a_n) * 16384 + ky * 8192) + a_c4;
    const int a_lds = a_n * A_STRIDE + a_c4 * 4;

    const uint16_t* pB = yTt + (size_t)(ky * 256) * 8192 + t * 8;
    const int b_s0 = t, b_s1 = t + 512;
    const int b_lds0 = (b_s0 >> 2) * B_STRIDE + (b_s0 & 3) * 8;
    const int b_lds1 = (b_s1 >> 2) * B_STRIDE + (b_s1 & 3) * 8;

    i32x4 a0 = __builtin_nontemporal_load(pa4);
    i32x4 q1 = __builtin_nontemporal_load(pa4 + 8);
    i32x4 q2 = __builtin_nontemporal_load(pa4 + 16);
    i32x4 q3 = __builtin_nontemporal_load(pa4 + 24);
    i32x4 aN = q3;
    pa4 += 32;
    uint4 b00 = *(const uint4*)(pB);
    uint4 b01 = *(const uint4*)(pB + 4096);
    pB += 8192;
    uint4 bC0 = *(const uint4*)(pB);
    uint4 bC1 = *(const uint4*)(pB + 4096);
    pB += 8192;
    uint4 bN0 = bC0, bN1 = bC1;

    int degp = a0.x + a0.y + a0.z + a0.w;
    {
        uint2 pv;
        pv.x = (uint32_t)(a0.x | (a0.y << 16)) * 0x3F80u;
        pv.y = (uint32_t)(a0.z | (a0.w << 16)) * 0x3F80u;
        *(uint2*)&As0[a_lds] = pv;
        *(uint4*)&Bs0[b_lds0] = b00;
        *(uint4*)&Bs0[b_lds1] = b01;
    }
    asm volatile("s_waitcnt lgkmcnt(0)\n\ts_barrier" ::: "memory");

    for (int kk = 0; kk < KITER - 4; kk += 3) {
        STEP(0, 0, 1, 1, kk);
        STEP(1, 1, 2, 2, kk + 1);
        STEP(2, 2, 0, 0, kk + 2);
    }
    STEP(0, 0, 1, 1, 252);
    STEP(1, 1, 2, 2, 253);
    STEP(2, 2, 0, 0, 254);
    STEP(0, 0, 1, 1, 255);

    degp += __shfl_down(degp, 4);
    degp += __shfl_down(degp, 2);
    degp += __shfl_down(degp, 1);
    if ((t & 7) == 0) degw[ky * 16384 + m0 + a_n] = degp;

    float* pc = part + (size_t)ky * 16384 * 256;
#pragma unroll
    for (int fr = 0; fr < 2; ++fr) {
#pragma unroll
        for (int r = 0; r < 4; ++r) {
            int m_l = wr * 32 + fr * 16 + quad * 4 + r;
            size_t mrow = (size_t)(m0 + m_l) * 256;
#pragma unroll
            for (int fc = 0; fc < 4; ++fc) {
                int n_g = wc * 64 + fc * 16 + l15;
                __builtin_nontemporal_store(acc[fr][fc][r], &pc[mrow + n_g]);
            }
        }
    }
}

// ---------------- K2X (MEASUREMENT): A-direct-to-register, B-DMA BK=64 dbuf
// Wave tile 16 rows x 128 cols; wr=w>>1 (0..3), wc=w&1.
// A: per-lane global->reg->bf16 (no LDS, no barrier coupling; 1-step dbuf).
// B: Bs[2][256*64] hw (64 KB), global_load_lds DMA, 8-slot XOR swizzle
//    (source + read, involution). vmcnt(4) before barrier: only B drained.
#define XSTEP(RD, WR, CUR, NXT, KK)                                            \
  do {                                                                         \
    if ((KK) < 127) {                                                          \
      gld_lds16(gB,        &BsX[WR][ldsb + 0]);                                \
      gld_lds16(gB + 2048, &BsX[WR][ldsb + 4096]);                             \
      gld_lds16(gB + 4096, &BsX[WR][ldsb + 8192]);                             \
      gld_lds16(gB + 6144, &BsX[WR][ldsb + 12288]);                            \
      gB += 16384;                                                             \
      aR[NXT][0] = __builtin_nontemporal_load(pa4);                            \
      aR[NXT][1] = __builtin_nontemporal_load(pa4 + 1);                        \
      aR[NXT][2] = __builtin_nontemporal_load(pa4 + 8);                        \
      aR[NXT][3] = __builtin_nontemporal_load(pa4 + 9);                        \
      pa4 += 16;                                                               \
      asm volatile("s_waitcnt vmcnt(8)" ::: "memory");                         \
    } else {                                                                   \
      asm volatile("s_waitcnt vmcnt(0)" ::: "memory");                         \
    }                                                                          \
    degp += aR[CUR][0].x + aR[CUR][0].y + aR[CUR][0].z + aR[CUR][0].w          \
          + aR[CUR][1].x + aR[CUR][1].y + aR[CUR][1].z + aR[CUR][1].w          \
          + aR[CUR][2].x + aR[CUR][2].y + aR[CUR][2].z + aR[CUR][2].w          \
          + aR[CUR][3].x + aR[CUR][3].y + aR[CUR][3].z + aR[CUR][3].w;         \
    _Pragma("unroll") for (int kh = 0; kh < 2; ++kh) {                         \
      uint4 u_;                                                                \
      u_.x = (uint32_t)(aR[CUR][2*kh].x   | (aR[CUR][2*kh].y   << 16)) * 0x3F80u; \
      u_.y = (uint32_t)(aR[CUR][2*kh].z   | (aR[CUR][2*kh].w   << 16)) * 0x3F80u; \
      u_.z = (uint32_t)(aR[CUR][2*kh+1].x | (aR[CUR][2*kh+1].y << 16)) * 0x3F80u; \
      u_.w = (uint32_t)(aR[CUR][2*kh+1].z | (aR[CUR][2*kh+1].w << 16)) * 0x3F80u; \
      bf16x8 af = *(bf16x8*)&u_;                                               \
      int bq = kh ? bq1 : bq0;                                                 \
      _Pragma("unroll") for (int fc = 0; fc < 8; ++fc) {                       \
        bf16x8 bfr = *(const bf16x8*)&BsX[RD][bn_base + fc * 1024 + bq];       \
        acc[fc] = __builtin_amdgcn_mfma_f32_16x16x32_bf16(af, bfr, acc[fc], 0, 0, 0); \
      }                                                                        \
    }                                                                          \
    if ((KK) < 127)                                                            \
      asm volatile("s_waitcnt vmcnt(4) lgkmcnt(0)\n\ts_barrier" ::: "memory"); \
  } while (0)

__global__ __launch_bounds__(512, 4) void k_big_gemm_x(const int* __restrict__ adj,
                                                       const uint16_t* __restrict__ yTt,
                                                       float* __restrict__ part2,
                                                       int* __restrict__ degw2) {
    __shared__ __align__(16) uint16_t BsX[2][256 * 64];   // 64 KB

    const int t = threadIdx.x;
    const int m0 = blockIdx.x * 64;
    const int ky = blockIdx.y;                     // 0/1, K-half 8192 = 128 steps
    const int lane = t & 63, w = t >> 6;
    const int wr = w >> 1, wc = w & 1;             // 16-row x 128-col wave tile
    const int l15 = lane & 15, quad = lane >> 4;

    f32x4 acc[8] = {};

    // A: lane owns row m0 + wr*16 + l15; per step 8 ints x 2 kh at quad*8
    const i32x4* pa4 =
        (const i32x4*)(adj + (size_t)(m0 + wr * 16 + l15) * 16384 + ky * 8192) + quad * 2;

    // B DMA: thread t stages 4 chunks c=t+512j; row n=c>>3, mem-slot t&7,
    // logical slot s_log = (t&7) ^ (n&7); same s_log for all j (n ≡ mod 8).
    const int n_t = t >> 3;
    const int s_log = (t & 7) ^ (n_t & 7);
    const uint16_t* gB = yTt + (size_t)(ky * 256) * 8192
                       + (size_t)(s_log >> 2) * 8192 + (size_t)n_t * 32 + (s_log & 3) * 8;
    const int ldsb = w * 512;                      // hw; +lane*8 by HW, +4096*j

    // B frag read (logical slot s = kh*4+quad, row n = wc*128+fc*16+l15):
    // mem byte = n*128 + ((s ^ (n&7))*16); n&7 == l15&7 for all fc.
    const int x7 = l15 & 7;
    const int bn_base = (wc * 128 + l15) * 64;
    const int bq0 = ((0 * 4 + quad) ^ x7) * 8;
    const int bq1 = ((1 * 4 + quad) ^ x7) * 8;

    i32x4 aR[2][4];
    int degp = 0;

    // ---- prologue: B(0) DMA -> BsX[0]; A(0) -> set0; vmcnt(4): B landed, A in flight
    gld_lds16(gB,        &BsX[0][ldsb + 0]);
    gld_lds16(gB + 2048, &BsX[0][ldsb + 4096]);
    gld_lds16(gB + 4096, &BsX[0][ldsb + 8192]);
    gld_lds16(gB + 6144, &BsX[0][ldsb + 12288]);
    gB += 16384;
    aR[0][0] = __builtin_nontemporal_load(pa4);
    aR[0][1] = __builtin_nontemporal_load(pa4 + 1);
    aR[0][2] = __builtin_nontemporal_load(pa4 + 8);
    aR[0][3] = __builtin_nontemporal_load(pa4 + 9);
    pa4 += 16;
    asm volatile("s_waitcnt vmcnt(4)\n\ts_barrier" ::: "memory");

    // ---- 128 steps; peel last pair so tail guards fold statically
    for (int k = 0; k < 126; k += 2) {
        XSTEP(0, 1, 0, 1, k);
        XSTEP(1, 0, 1, 0, k + 1);
    }
    XSTEP(0, 1, 0, 1, 126);
    XSTEP(1, 0, 1, 0, 127);

    // deg: reduce across quads (wc==0 wave only writes; both computed it)
    degp += __shfl_down(degp, 32);
    degp += __shfl_down(degp, 16);
    if (wc == 0 && quad == 0)
        degw2[ky * 16384 + m0 + wr * 16 + l15] = degp;

    // C epilogue (C/D layout: col=lane&15, row=quad*4+reg)
    float* pc = part2 + (size_t)ky * 16384 * 256;
#pragma unroll
    for (int fc = 0; fc < 8; ++fc) {
#pragma unroll
        for (int r = 0; r < 4; ++r) {
            int row = m0 + wr * 16 + quad * 4 + r;
            int col = wc * 128 + fc * 16 + l15;
            __builtin_nontemporal_store(acc[fc][r], &pc[(size_t)row * 256 + col]);
        }
    }
}

// ---------------- K3: out = (p0+p1)/(d0+d1) + z
__global__ __launch_bounds__(256) void k_reduce(const float* __restrict__ part,
                                                const int* __restrict__ degw,
                                                const float* __restrict__ z,
                                                float* __restrict__ out) {
    int i4 = blockIdx.x * 256 + threadIdx.x;       // float4 index, 64 per row
    int m = i4 >> 6;
    float4 p0 = ((const float4*)part)[i4];
    float4 p1 = ((const float4*)part)[i4 + 16384 * 64];
    float4 zz = ((const float4*)z)[i4];
    float inv = 1.0f / (float)(degw[m] + degw[16384 + m]);
    float4 o;
    o.x = (p0.x + p1.x) * inv + zz.x;
    o.y = (p0.y + p1.y) * inv + zz.y;
    o.z = (p0.z + p1.z) * inv + zz.z;
    o.w = (p0.w + p1.w) * inv + zz.w;
    ((float4*)out)[i4] = o;
}

extern "C" void kernel_launch(void* const* d_in, const int* in_sizes, int n_in,
                              void* d_out, int out_size, void* d_ws, size_t ws_size,
                              hipStream_t stream) {
    const float* x      = (const float*)d_in[0];
    const int*   adj    = (const int*)d_in[1];
    const float* weight = (const float*)d_in[2];
    const float* bias   = (const float*)d_in[3];
    float* out = (float*)d_out;

    // ws: WT 256KB | yTt 8MB | z 16MB | part 32MB | degw 128KB
    // scratch (measurement only): part2 @64MB (32MB), degw2 @96MB (128KB)
    char* wsb = (char*)d_ws;
    uint16_t* wt    = (uint16_t*)(wsb);
    uint16_t* yTt   = (uint16_t*)(wsb + 262144);
    float*    z     = (float*)(wsb + 262144 + 8388608);
    float*    partb = (float*)(wsb + 262144 + 8388608 + 16777216);
    int*      degw  = (int*)(wsb + 262144 + 8388608 + 16777216 + 33554432);
    float*    part2 = (float*)(wsb + (size_t)64 * 1024 * 1024);
    int*      degw2 = (int*)(wsb + (size_t)96 * 1024 * 1024);

    k_transpose_w<<<512, 256, 0, stream>>>(weight, wt);
    k_small_gemm<<<dim3(4, 128), 256, 0, stream>>>(x, wt, bias, yTt, z);
    k_big_gemm<<<dim3(256, 2), 512, 0, stream>>>(adj, yTt, partb, degw);
    k_reduce<<<4096, 256, 0, stream>>>(partb, degw, z, out);
    // measurement launch (scratch output; real pipeline above is untouched)
    k_big_gemm_x<<<dim3(256, 2), 512, 0, stream>>>(adj, yTt, part2, degw2);
}

// Round 7
// 1604.913 us; speedup vs baseline: 1.1650x; 1.1650x over previous
//
#include <hip/hip_runtime.h>
#include <hip/hip_bf16.h>
#include <stdint.h>

// GraphSAGE layer, N=16384, F_IN=F_OUT=256.
// out = (adj@ (x@W1))/deg + x@W2 + bias
//   K0: WT[n][k] (bf16)  = transpose of [W1|W2]
//   K1: yTt[j/32][n][32] (bf16, K-TILED) = (x@W1)^T ; z[m][n] = x@W2 + bias
//   K2 v14 (promoted from round-6 measurement kernel K2X, 444.5 us measured
//       within-probe vs ~650 us for the v9/v12 convoy):
//       A-DIRECT-TO-REGISTER: each lane owns one adj row; 8x dwordx4 nt
//       loads per step, double-buffered in regs, drained by counted
//       vmcnt(8) one step later — A never touches LDS and never couples
//       to the barrier. Barriers/LDS serve only B: BK=64, Bs[2][256*64]
//       (64 KB dbuf) via global_load_lds w16, 8-slot XOR swizzle
//       (inverse-swizzled global source + swizzled ds_read; LDS dest
//       linear per rule #21). vmcnt(4) before each barrier = only B
//       drained; A loads stay in flight across barriers. 128 steps.
//       Wave tile 16x128 (wr=w>>1, wc=w&1), grid (256,2) split-K halves.
//   K3: out = (p0+p1)/(d0+d1) + z

typedef short bf16x8 __attribute__((ext_vector_type(8)));
typedef float f32x4  __attribute__((ext_vector_type(4)));
typedef int   i32x4  __attribute__((ext_vector_type(4)));

__device__ __forceinline__ uint32_t pack_bf16_rne(float lo, float hi) {
    uint32_t ul = __float_as_uint(lo);
    uint32_t uh = __float_as_uint(hi);
    ul = (ul + 0x7fffu + ((ul >> 16) & 1u)) >> 16;
    uh = (uh + 0x7fffu + ((uh >> 16) & 1u)) >> 16;
    return ul | (uh << 16);
}

__device__ __forceinline__ void gld_lds16(const uint16_t* g, uint16_t* l) {
    __builtin_amdgcn_global_load_lds(
        (const __attribute__((address_space(1))) void*)g,
        (__attribute__((address_space(3))) void*)l, 16, 0, 0);
}

// ---------------- K0: transpose weight [512,256] f32 -> WT [512(n)][256(k)] bf16
__global__ __launch_bounds__(256) void k_transpose_w(const float* __restrict__ w,
                                                     uint16_t* __restrict__ wt) {
    int idx = blockIdx.x * 256 + threadIdx.x;   // 0..131071
    int n = idx >> 8;
    int k = idx & 255;
    int row = (n < 256) ? k : (256 + k);
    int col = (n < 256) ? n : (n - 256);
    uint32_t u = __float_as_uint(w[row * 256 + col]);
    u = (u + 0x7fffu + ((u >> 16) & 1u)) >> 16;
    wt[idx] = (uint16_t)u;
}

// ---------------- K1: small GEMM  [16384,256] @ [256,512]
__global__ __launch_bounds__(256) void k_small_gemm(const float* __restrict__ x,
                                                    const uint16_t* __restrict__ wt,
                                                    const float* __restrict__ bias,
                                                    uint16_t* __restrict__ yTt,
                                                    float* __restrict__ z) {
    __shared__ uint16_t As[128 * 32];  // [m][k] bf16
    __shared__ uint16_t Bs[128 * 32];  // [n][k] bf16

    const int t  = threadIdx.x;
    const int ct = blockIdx.x;        // 0..3
    const int rt = blockIdx.y;        // 0..127
    const int m0 = rt * 128;
    const int n0 = ct * 128;

    const int lane = t & 63, w = t >> 6;
    const int wr = w >> 1, wc = w & 1;
    const int l15 = lane & 15, quad = lane >> 4;

    f32x4 acc[4][4] = {};

    float4 a_reg[4];
    uint4  b_reg[2];

#pragma unroll
    for (int i = 0; i < 4; ++i) {
        int f4 = t + 256 * i, row = f4 >> 3, c4 = f4 & 7;
        a_reg[i] = *(const float4*)(x + (m0 + row) * 256 + c4 * 4);
    }
#pragma unroll
    for (int i = 0; i < 2; ++i) {
        int u4 = t + 256 * i, n_l = u4 >> 2, part = u4 & 3;
        b_reg[i] = *(const uint4*)(wt + (n0 + n_l) * 256 + part * 8);
    }

    for (int kk = 0; kk < 8; ++kk) {
        __syncthreads();
#pragma unroll
        for (int i = 0; i < 4; ++i) {
            int f4 = t + 256 * i, row = f4 >> 3, c4 = f4 & 7;
            uint2 p;
            p.x = pack_bf16_rne(a_reg[i].x, a_reg[i].y);
            p.y = pack_bf16_rne(a_reg[i].z, a_reg[i].w);
            *(uint2*)(As + row * 32 + c4 * 4) = p;
        }
#pragma unroll
        for (int i = 0; i < 2; ++i) {
            int u4 = t + 256 * i, n_l = u4 >> 2, part = u4 & 3;
            *(uint4*)(Bs + n_l * 32 + part * 8) = b_reg[i];
        }
        if (kk < 7) {
            int k0 = (kk + 1) * 32;
#pragma unroll
            for (int i = 0; i < 4; ++i) {
                int f4 = t + 256 * i, row = f4 >> 3, c4 = f4 & 7;
                a_reg[i] = *(const float4*)(x + (m0 + row) * 256 + k0 + c4 * 4);
            }
#pragma unroll
            for (int i = 0; i < 2; ++i) {
                int u4 = t + 256 * i, n_l = u4 >> 2, part = u4 & 3;
                b_reg[i] = *(const uint4*)(wt + (n0 + n_l) * 256 + k0 + part * 8);
            }
        }
        __syncthreads();

        bf16x8 a_frag[4], b_frag[4];
#pragma unroll
        for (int fr = 0; fr < 4; ++fr)
            a_frag[fr] = *(const bf16x8*)(As + (wr * 64 + fr * 16 + l15) * 32 + quad * 8);
#pragma unroll
        for (int fc = 0; fc < 4; ++fc)
            b_frag[fc] = *(const bf16x8*)(Bs + (wc * 64 + fc * 16 + l15) * 32 + quad * 8);
#pragma unroll
        for (int fr = 0; fr < 4; ++fr)
#pragma unroll
            for (int fc = 0; fc < 4; ++fc)
                acc[fr][fc] = __builtin_amdgcn_mfma_f32_16x16x32_bf16(
                    a_frag[fr], b_frag[fc], acc[fr][fc], 0, 0, 0);
    }

    if (ct < 2) {
#pragma unroll
        for (int fr = 0; fr < 4; ++fr) {
            int m_base = m0 + wr * 64 + fr * 16 + quad * 4;
#pragma unroll
            for (int fc = 0; fc < 4; ++fc) {
                int n_g = n0 + wc * 64 + fc * 16 + l15;   // 0..255
                uint2 pp;
                pp.x = pack_bf16_rne(acc[fr][fc][0], acc[fr][fc][1]);
                pp.y = pack_bf16_rne(acc[fr][fc][2], acc[fr][fc][3]);
                *(uint2*)(yTt + (size_t)(m_base >> 5) * 8192 + n_g * 32 + (m_base & 31)) = pp;
            }
        }
    } else {
#pragma unroll
        for (int fr = 0; fr < 4; ++fr) {
            int m_base = m0 + wr * 64 + fr * 16 + quad * 4;
#pragma unroll
            for (int fc = 0; fc < 4; ++fc) {
                int n_g = (n0 - 256) + wc * 64 + fc * 16 + l15;  // 0..255
                float bv = bias[n_g];
#pragma unroll
                for (int r = 0; r < 4; ++r)
                    z[(size_t)(m_base + r) * 256 + n_g] = acc[fr][fc][r] + bv;
            }
        }
    }
}

// ---------------- K2 v14: A-direct-to-register, B-DMA BK=64 dbuf
#define XSTEP(RD, WR, CUR, NXT, KK)                                            \
  do {                                                                         \
    if ((KK) < 127) {                                                          \
      gld_lds16(gB,        &BsX[WR][ldsb + 0]);                                \
      gld_lds16(gB + 2048, &BsX[WR][ldsb + 4096]);                             \
      gld_lds16(gB + 4096, &BsX[WR][ldsb + 8192]);                             \
      gld_lds16(gB + 6144, &BsX[WR][ldsb + 12288]);                            \
      gB += 16384;                                                             \
      aR[NXT][0] = __builtin_nontemporal_load(pa4);                            \
      aR[NXT][1] = __builtin_nontemporal_load(pa4 + 1);                        \
      aR[NXT][2] = __builtin_nontemporal_load(pa4 + 8);                        \
      aR[NXT][3] = __builtin_nontemporal_load(pa4 + 9);                        \
      pa4 += 16;                                                               \
      asm volatile("s_waitcnt vmcnt(8)" ::: "memory");                         \
    } else {                                                                   \
      asm volatile("s_waitcnt vmcnt(0)" ::: "memory");                         \
    }                                                                          \
    degp += aR[CUR][0].x + aR[CUR][0].y + aR[CUR][0].z + aR[CUR][0].w          \
          + aR[CUR][1].x + aR[CUR][1].y + aR[CUR][1].z + aR[CUR][1].w          \
          + aR[CUR][2].x + aR[CUR][2].y + aR[CUR][2].z + aR[CUR][2].w          \
          + aR[CUR][3].x + aR[CUR][3].y + aR[CUR][3].z + aR[CUR][3].w;         \
    _Pragma("unroll") for (int kh = 0; kh < 2; ++kh) {                         \
      uint4 u_;                                                                \
      u_.x = (uint32_t)(aR[CUR][2*kh].x   | (aR[CUR][2*kh].y   << 16)) * 0x3F80u; \
      u_.y = (uint32_t)(aR[CUR][2*kh].z   | (aR[CUR][2*kh].w   << 16)) * 0x3F80u; \
      u_.z = (uint32_t)(aR[CUR][2*kh+1].x | (aR[CUR][2*kh+1].y << 16)) * 0x3F80u; \
      u_.w = (uint32_t)(aR[CUR][2*kh+1].z | (aR[CUR][2*kh+1].w << 16)) * 0x3F80u; \
      bf16x8 af = *(bf16x8*)&u_;                                               \
      int bq = kh ? bq1 : bq0;                                                 \
      _Pragma("unroll") for (int fc = 0; fc < 8; ++fc) {                       \
        bf16x8 bfr = *(const bf16x8*)&BsX[RD][bn_base + fc * 1024 + bq];       \
        acc[fc] = __builtin_amdgcn_mfma_f32_16x16x32_bf16(af, bfr, acc[fc], 0, 0, 0); \
      }                                                                        \
    }                                                                          \
    if ((KK) < 127)                                                            \
      asm volatile("s_waitcnt vmcnt(4) lgkmcnt(0)\n\ts_barrier" ::: "memory"); \
  } while (0)

__global__ __launch_bounds__(512, 4) void k_big_gemm(const int* __restrict__ adj,
                                                     const uint16_t* __restrict__ yTt,
                                                     float* __restrict__ part,
                                                     int* __restrict__ degw) {
    __shared__ __align__(16) uint16_t BsX[2][256 * 64];   // 64 KB

    const int t = threadIdx.x;
    const int m0 = blockIdx.x * 64;
    const int ky = blockIdx.y;                     // 0/1, K-half 8192 = 128 steps
    const int lane = t & 63, w = t >> 6;
    const int wr = w >> 1, wc = w & 1;             // 16-row x 128-col wave tile
    const int l15 = lane & 15, quad = lane >> 4;

    f32x4 acc[8] = {};

    // A: lane owns row m0 + wr*16 + l15; per step 8 ints x 2 kh at quad*8
    const i32x4* pa4 =
        (const i32x4*)(adj + (size_t)(m0 + wr * 16 + l15) * 16384 + ky * 8192) + quad * 2;

    // B DMA: thread t stages 4 chunks c=t+512j; row n=c>>3 (n==t>>3 mod 8),
    // mem-slot t&7 holds logical slot s_log=(t&7)^(n&7) (XOR involution;
    // LDS dest linear, source pre-inverse-swizzled).
    const int n_t = t >> 3;
    const int s_log = (t & 7) ^ (n_t & 7);
    const uint16_t* gB = yTt + (size_t)(ky * 256) * 8192
                       + (size_t)(s_log >> 2) * 8192 + (size_t)n_t * 32 + (s_log & 3) * 8;
    const int ldsb = w * 512;                      // hw; +lane*8 by HW, +4096*j

    // B frag read (logical slot s = kh*4+quad, row n = wc*128+fc*16+l15):
    // mem hw = n*64 + ((s ^ (n&7))*8); n&7 == l15&7 for all fc.
    const int x7 = l15 & 7;
    const int bn_base = (wc * 128 + l15) * 64;
    const int bq0 = ((0 * 4 + quad) ^ x7) * 8;
    const int bq1 = ((1 * 4 + quad) ^ x7) * 8;

    i32x4 aR[2][4];
    int degp = 0;

    // ---- prologue: B(0) DMA -> BsX[0]; A(0) -> set0; vmcnt(4): B landed, A in flight
    gld_lds16(gB,        &BsX[0][ldsb + 0]);
    gld_lds16(gB + 2048, &BsX[0][ldsb + 4096]);
    gld_lds16(gB + 4096, &BsX[0][ldsb + 8192]);
    gld_lds16(gB + 6144, &BsX[0][ldsb + 12288]);
    gB += 16384;
    aR[0][0] = __builtin_nontemporal_load(pa4);
    aR[0][1] = __builtin_nontemporal_load(pa4 + 1);
    aR[0][2] = __builtin_nontemporal_load(pa4 + 8);
    aR[0][3] = __builtin_nontemporal_load(pa4 + 9);
    pa4 += 16;
    asm volatile("s_waitcnt vmcnt(4)\n\ts_barrier" ::: "memory");

    // ---- 128 steps; peel last pair so tail guards fold statically
    for (int k = 0; k < 126; k += 2) {
        XSTEP(0, 1, 0, 1, k);
        XSTEP(1, 0, 1, 0, k + 1);
    }
    XSTEP(0, 1, 0, 1, 126);
    XSTEP(1, 0, 1, 0, 127);

    // deg: lane's row summed over its quad-slices; reduce across quads
    degp += __shfl_down(degp, 32);
    degp += __shfl_down(degp, 16);
    if (wc == 0 && quad == 0)
        degw[ky * 16384 + m0 + wr * 16 + l15] = degp;

    // C epilogue (C/D layout: col=lane&15, row=quad*4+reg)
    float* pc = part + (size_t)ky * 16384 * 256;
#pragma unroll
    for (int fc = 0; fc < 8; ++fc) {
#pragma unroll
        for (int r = 0; r < 4; ++r) {
            int row = m0 + wr * 16 + quad * 4 + r;
            int col = wc * 128 + fc * 16 + l15;
            __builtin_nontemporal_store(acc[fc][r], &pc[(size_t)row * 256 + col]);
        }
    }
}

// ---------------- K3: out = (p0+p1)/(d0+d1) + z
__global__ __launch_bounds__(256) void k_reduce(const float* __restrict__ part,
                                                const int* __restrict__ degw,
                                                const float* __restrict__ z,
                                                float* __restrict__ out) {
    int i4 = blockIdx.x * 256 + threadIdx.x;       // float4 index, 64 per row
    int m = i4 >> 6;
    float4 p0 = ((const float4*)part)[i4];
    float4 p1 = ((const float4*)part)[i4 + 16384 * 64];
    float4 zz = ((const float4*)z)[i4];
    float inv = 1.0f / (float)(degw[m] + degw[16384 + m]);
    float4 o;
    o.x = (p0.x + p1.x) * inv + zz.x;
    o.y = (p0.y + p1.y) * inv + zz.y;
    o.z = (p0.z + p1.z) * inv + zz.z;
    o.w = (p0.w + p1.w) * inv + zz.w;
    ((float4*)out)[i4] = o;
}

extern "C" void kernel_launch(void* const* d_in, const int* in_sizes, int n_in,
                              void* d_out, int out_size, void* d_ws, size_t ws_size,
                              hipStream_t stream) {
    const float* x      = (const float*)d_in[0];
    const int*   adj    = (const int*)d_in[1];
    const float* weight = (const float*)d_in[2];
    const float* bias   = (const float*)d_in[3];
    float* out = (float*)d_out;

    // ws: WT 256KB | yTt 8MB | z 16MB | part 32MB | degw 128KB
    char* wsb = (char*)d_ws;
    uint16_t* wt    = (uint16_t*)(wsb);
    uint16_t* yTt   = (uint16_t*)(wsb + 262144);
    float*    z     = (float*)(wsb + 262144 + 8388608);
    float*    partb = (float*)(wsb + 262144 + 8388608 + 16777216);
    int*      degw  = (int*)(wsb + 262144 + 8388608 + 16777216 + 33554432);

    k_transpose_w<<<512, 256, 0, stream>>>(weight, wt);
    k_small_gemm<<<dim3(4, 128), 256, 0, stream>>>(x, wt, bias, yTt, z);
    k_big_gemm<<<dim3(256, 2), 512, 0, stream>>>(adj, yTt, partb, degw);
    k_reduce<<<4096, 256, 0, stream>>>(partb, degw, z, out);
}

// Round 8
// 1601.240 us; speedup vs baseline: 1.1677x; 1.0023x over previous
//
#include <hip/hip_runtime.h>
#include <hip/hip_bf16.h>
#include <stdint.h>

// GraphSAGE layer, N=16384, F_IN=F_OUT=256.
// out = (adj@ (x@W1))/deg + x@W2 + bias
//   K0: WT[n][k] (bf16)  = transpose of [W1|W2]
//   K1: yTt[j/32][n][32] (bf16, K-TILED) = (x@W1)^T ; z[m][n] = x@W2 + bias
//   K2 v15 = round-7 v14 (A-direct-to-register, B-DMA BK=64 dbuf) + the
//       ky-per-XCD-half swizzle proven in v12: xcd = linear_id & 7 [m09],
//       ky = xcd>>2 -> each XCD's 64 blocks all read the SAME 4 MB yTt
//       half = exactly its private L2. B re-reads (2.1 GB aggregate) move
//       L3 -> local L2, removing them from the HBM/L3 window that the
//       harness's 4.29 GB poison fill contends for (R6 vs R7 isolated the
//       fill-overlap mechanism: identical K2X = 444 us at pipeline tail
//       vs ~860 us in slot 2).
//       A: per-lane 8x dwordx4 nt loads/step, reg-dbuf, counted vmcnt(8);
//       B: Bs[2][256*64] (64 KB) via global_load_lds w16, 8-slot XOR
//       swizzle (inverse-swizzled source + swizzled read, linear dest);
//       vmcnt(4) before each barrier (only B drained). 128 steps.
//   K3: out = (p0+p1)/(d0+d1) + z

typedef short bf16x8 __attribute__((ext_vector_type(8)));
typedef float f32x4  __attribute__((ext_vector_type(4)));
typedef int   i32x4  __attribute__((ext_vector_type(4)));

__device__ __forceinline__ uint32_t pack_bf16_rne(float lo, float hi) {
    uint32_t ul = __float_as_uint(lo);
    uint32_t uh = __float_as_uint(hi);
    ul = (ul + 0x7fffu + ((ul >> 16) & 1u)) >> 16;
    uh = (uh + 0x7fffu + ((uh >> 16) & 1u)) >> 16;
    return ul | (uh << 16);
}

__device__ __forceinline__ void gld_lds16(const uint16_t* g, uint16_t* l) {
    __builtin_amdgcn_global_load_lds(
        (const __attribute__((address_space(1))) void*)g,
        (__attribute__((address_space(3))) void*)l, 16, 0, 0);
}

// ---------------- K0: transpose weight [512,256] f32 -> WT [512(n)][256(k)] bf16
__global__ __launch_bounds__(256) void k_transpose_w(const float* __restrict__ w,
                                                     uint16_t* __restrict__ wt) {
    int idx = blockIdx.x * 256 + threadIdx.x;   // 0..131071
    int n = idx >> 8;
    int k = idx & 255;
    int row = (n < 256) ? k : (256 + k);
    int col = (n < 256) ? n : (n - 256);
    uint32_t u = __float_as_uint(w[row * 256 + col]);
    u = (u + 0x7fffu + ((u >> 16) & 1u)) >> 16;
    wt[idx] = (uint16_t)u;
}

// ---------------- K1: small GEMM  [16384,256] @ [256,512]
__global__ __launch_bounds__(256) void k_small_gemm(const float* __restrict__ x,
                                                    const uint16_t* __restrict__ wt,
                                                    const float* __restrict__ bias,
                                                    uint16_t* __restrict__ yTt,
                                                    float* __restrict__ z) {
    __shared__ uint16_t As[128 * 32];  // [m][k] bf16
    __shared__ uint16_t Bs[128 * 32];  // [n][k] bf16

    const int t  = threadIdx.x;
    const int ct = blockIdx.x;        // 0..3
    const int rt = blockIdx.y;        // 0..127
    const int m0 = rt * 128;
    const int n0 = ct * 128;

    const int lane = t & 63, w = t >> 6;
    const int wr = w >> 1, wc = w & 1;
    const int l15 = lane & 15, quad = lane >> 4;

    f32x4 acc[4][4] = {};

    float4 a_reg[4];
    uint4  b_reg[2];

#pragma unroll
    for (int i = 0; i < 4; ++i) {
        int f4 = t + 256 * i, row = f4 >> 3, c4 = f4 & 7;
        a_reg[i] = *(const float4*)(x + (m0 + row) * 256 + c4 * 4);
    }
#pragma unroll
    for (int i = 0; i < 2; ++i) {
        int u4 = t + 256 * i, n_l = u4 >> 2, part = u4 & 3;
        b_reg[i] = *(const uint4*)(wt + (n0 + n_l) * 256 + part * 8);
    }

    for (int kk = 0; kk < 8; ++kk) {
        __syncthreads();
#pragma unroll
        for (int i = 0; i < 4; ++i) {
            int f4 = t + 256 * i, row = f4 >> 3, c4 = f4 & 7;
            uint2 p;
            p.x = pack_bf16_rne(a_reg[i].x, a_reg[i].y);
            p.y = pack_bf16_rne(a_reg[i].z, a_reg[i].w);
            *(uint2*)(As + row * 32 + c4 * 4) = p;
        }
#pragma unroll
        for (int i = 0; i < 2; ++i) {
            int u4 = t + 256 * i, n_l = u4 >> 2, part = u4 & 3;
            *(uint4*)(Bs + n_l * 32 + part * 8) = b_reg[i];
        }
        if (kk < 7) {
            int k0 = (kk + 1) * 32;
#pragma unroll
            for (int i = 0; i < 4; ++i) {
                int f4 = t + 256 * i, row = f4 >> 3, c4 = f4 & 7;
                a_reg[i] = *(const float4*)(x + (m0 + row) * 256 + k0 + c4 * 4);
            }
#pragma unroll
            for (int i = 0; i < 2; ++i) {
                int u4 = t + 256 * i, n_l = u4 >> 2, part = u4 & 3;
                b_reg[i] = *(const uint4*)(wt + (n0 + n_l) * 256 + k0 + part * 8);
            }
        }
        __syncthreads();

        bf16x8 a_frag[4], b_frag[4];
#pragma unroll
        for (int fr = 0; fr < 4; ++fr)
            a_frag[fr] = *(const bf16x8*)(As + (wr * 64 + fr * 16 + l15) * 32 + quad * 8);
#pragma unroll
        for (int fc = 0; fc < 4; ++fc)
            b_frag[fc] = *(const bf16x8*)(Bs + (wc * 64 + fc * 16 + l15) * 32 + quad * 8);
#pragma unroll
        for (int fr = 0; fr < 4; ++fr)
#pragma unroll
            for (int fc = 0; fc < 4; ++fc)
                acc[fr][fc] = __builtin_amdgcn_mfma_f32_16x16x32_bf16(
                    a_frag[fr], b_frag[fc], acc[fr][fc], 0, 0, 0);
    }

    if (ct < 2) {
#pragma unroll
        for (int fr = 0; fr < 4; ++fr) {
            int m_base = m0 + wr * 64 + fr * 16 + quad * 4;
#pragma unroll
            for (int fc = 0; fc < 4; ++fc) {
                int n_g = n0 + wc * 64 + fc * 16 + l15;   // 0..255
                uint2 pp;
                pp.x = pack_bf16_rne(acc[fr][fc][0], acc[fr][fc][1]);
                pp.y = pack_bf16_rne(acc[fr][fc][2], acc[fr][fc][3]);
                *(uint2*)(yTt + (size_t)(m_base >> 5) * 8192 + n_g * 32 + (m_base & 31)) = pp;
            }
        }
    } else {
#pragma unroll
        for (int fr = 0; fr < 4; ++fr) {
            int m_base = m0 + wr * 64 + fr * 16 + quad * 4;
#pragma unroll
            for (int fc = 0; fc < 4; ++fc) {
                int n_g = (n0 - 256) + wc * 64 + fc * 16 + l15;  // 0..255
                float bv = bias[n_g];
#pragma unroll
                for (int r = 0; r < 4; ++r)
                    z[(size_t)(m_base + r) * 256 + n_g] = acc[fr][fc][r] + bv;
            }
        }
    }
}

// ---------------- K2 v15: A-direct-to-register, B-DMA BK=64 dbuf, XCD-ky swizzle
#define XSTEP(RD, WR, CUR, NXT, KK)                                            \
  do {                                                                         \
    if ((KK) < 127) {                                                          \
      gld_lds16(gB,        &BsX[WR][ldsb + 0]);                                \
      gld_lds16(gB + 2048, &BsX[WR][ldsb + 4096]);                             \
      gld_lds16(gB + 4096, &BsX[WR][ldsb + 8192]);                             \
      gld_lds16(gB + 6144, &BsX[WR][ldsb + 12288]);                            \
      gB += 16384;                                                             \
      aR[NXT][0] = __builtin_nontemporal_load(pa4);                            \
      aR[NXT][1] = __builtin_nontemporal_load(pa4 + 1);                        \
      aR[NXT][2] = __builtin_nontemporal_load(pa4 + 8);                        \
      aR[NXT][3] = __builtin_nontemporal_load(pa4 + 9);                        \
      pa4 += 16;                                                               \
      asm volatile("s_waitcnt vmcnt(8)" ::: "memory");                         \
    } else {                                                                   \
      asm volatile("s_waitcnt vmcnt(0)" ::: "memory");                         \
    }                                                                          \
    degp += aR[CUR][0].x + aR[CUR][0].y + aR[CUR][0].z + aR[CUR][0].w          \
          + aR[CUR][1].x + aR[CUR][1].y + aR[CUR][1].z + aR[CUR][1].w          \
          + aR[CUR][2].x + aR[CUR][2].y + aR[CUR][2].z + aR[CUR][2].w          \
          + aR[CUR][3].x + aR[CUR][3].y + aR[CUR][3].z + aR[CUR][3].w;         \
    _Pragma("unroll") for (int kh = 0; kh < 2; ++kh) {                         \
      uint4 u_;                                                                \
      u_.x = (uint32_t)(aR[CUR][2*kh].x   | (aR[CUR][2*kh].y   << 16)) * 0x3F80u; \
      u_.y = (uint32_t)(aR[CUR][2*kh].z   | (aR[CUR][2*kh].w   << 16)) * 0x3F80u; \
      u_.z = (uint32_t)(aR[CUR][2*kh+1].x | (aR[CUR][2*kh+1].y << 16)) * 0x3F80u; \
      u_.w = (uint32_t)(aR[CUR][2*kh+1].z | (aR[CUR][2*kh+1].w << 16)) * 0x3F80u; \
      bf16x8 af = *(bf16x8*)&u_;                                               \
      int bq = kh ? bq1 : bq0;                                                 \
      _Pragma("unroll") for (int fc = 0; fc < 8; ++fc) {                       \
        bf16x8 bfr = *(const bf16x8*)&BsX[RD][bn_base + fc * 1024 + bq];       \
        acc[fc] = __builtin_amdgcn_mfma_f32_16x16x32_bf16(af, bfr, acc[fc], 0, 0, 0); \
      }                                                                        \
    }                                                                          \
    if ((KK) < 127)                                                            \
      asm volatile("s_waitcnt vmcnt(4) lgkmcnt(0)\n\ts_barrier" ::: "memory"); \
  } while (0)

__global__ __launch_bounds__(512, 4) void k_big_gemm(const int* __restrict__ adj,
                                                     const uint16_t* __restrict__ yTt,
                                                     float* __restrict__ part,
                                                     int* __restrict__ degw) {
    __shared__ __align__(16) uint16_t BsX[2][256 * 64];   // 64 KB

    const int t = threadIdx.x;
    // XCD-aware remap [m09: xcd = linear_id & 7]: XCDs 0-3 own ky=0,
    // XCDs 4-7 own ky=1 -> each XCD's B working set = 4 MB = its L2.
    // Bijective over 512 blocks: (xcd&3) in 0..3, slot in 0..63.
    const int id   = blockIdx.x + (int)gridDim.x * blockIdx.y;  // 0..511
    const int xcd  = id & 7, slot = id >> 3;                    // slot 0..63
    const int ky   = xcd >> 2;                                  // 0/1
    const int m0   = ((xcd & 3) * 64 + slot) * 64;              // 0..16320
    const int lane = t & 63, w = t >> 6;
    const int wr = w >> 1, wc = w & 1;             // 16-row x 128-col wave tile
    const int l15 = lane & 15, quad = lane >> 4;

    f32x4 acc[8] = {};

    // A: lane owns row m0 + wr*16 + l15; per step 8 ints x 2 kh at quad*8
    const i32x4* pa4 =
        (const i32x4*)(adj + (size_t)(m0 + wr * 16 + l15) * 16384 + ky * 8192) + quad * 2;

    // B DMA: thread t stages 4 chunks c=t+512j; row n=c>>3 (n==t>>3 mod 8),
    // mem-slot t&7 holds logical slot s_log=(t&7)^(n&7) (XOR involution;
    // LDS dest linear, source pre-inverse-swizzled).
    const int n_t = t >> 3;
    const int s_log = (t & 7) ^ (n_t & 7);
    const uint16_t* gB = yTt + (size_t)(ky * 256) * 8192
                       + (size_t)(s_log >> 2) * 8192 + (size_t)n_t * 32 + (s_log & 3) * 8;
    const int ldsb = w * 512;                      // hw; +lane*8 by HW, +4096*j

    // B frag read (logical slot s = kh*4+quad, row n = wc*128+fc*16+l15):
    // mem hw = n*64 + ((s ^ (n&7))*8); n&7 == l15&7 for all fc.
    const int x7 = l15 & 7;
    const int bn_base = (wc * 128 + l15) * 64;
    const int bq0 = ((0 * 4 + quad) ^ x7) * 8;
    const int bq1 = ((1 * 4 + quad) ^ x7) * 8;

    i32x4 aR[2][4];
    int degp = 0;

    // ---- prologue: B(0) DMA -> BsX[0]; A(0) -> set0; vmcnt(4): B landed, A in flight
    gld_lds16(gB,        &BsX[0][ldsb + 0]);
    gld_lds16(gB + 2048, &BsX[0][ldsb + 4096]);
    gld_lds16(gB + 4096, &BsX[0][ldsb + 8192]);
    gld_lds16(gB + 6144, &BsX[0][ldsb + 12288]);
    gB += 16384;
    aR[0][0] = __builtin_nontemporal_load(pa4);
    aR[0][1] = __builtin_nontemporal_load(pa4 + 1);
    aR[0][2] = __builtin_nontemporal_load(pa4 + 8);
    aR[0][3] = __builtin_nontemporal_load(pa4 + 9);
    pa4 += 16;
    asm volatile("s_waitcnt vmcnt(4)\n\ts_barrier" ::: "memory");

    // ---- 128 steps; peel last pair so tail guards fold statically
    for (int k = 0; k < 126; k += 2) {
        XSTEP(0, 1, 0, 1, k);
        XSTEP(1, 0, 1, 0, k + 1);
    }
    XSTEP(0, 1, 0, 1, 126);
    XSTEP(1, 0, 1, 0, 127);

    // deg: lane's row summed over its quad-slices; reduce across quads
    degp += __shfl_down(degp, 32);
    degp += __shfl_down(degp, 16);
    if (wc == 0 && quad == 0)
        degw[ky * 16384 + m0 + wr * 16 + l15] = degp;

    // C epilogue (C/D layout: col=lane&15, row=quad*4+reg)
    float* pc = part + (size_t)ky * 16384 * 256;
#pragma unroll
    for (int fc = 0; fc < 8; ++fc) {
#pragma unroll
        for (int r = 0; r < 4; ++r) {
            int row = m0 + wr * 16 + quad * 4 + r;
            int col = wc * 128 + fc * 16 + l15;
            __builtin_nontemporal_store(acc[fc][r], &pc[(size_t)row * 256 + col]);
        }
    }
}

// ---------------- K3: out = (p0+p1)/(d0+d1) + z
__global__ __launch_bounds__(256) void k_reduce(const float* __restrict__ part,
                                                const int* __restrict__ degw,
                                                const float* __restrict__ z,
                                                float* __restrict__ out) {
    int i4 = blockIdx.x * 256 + threadIdx.x;       // float4 index, 64 per row
    int m = i4 >> 6;
    float4 p0 = ((const float4*)part)[i4];
    float4 p1 = ((const float4*)part)[i4 + 16384 * 64];
    float4 zz = ((const float4*)z)[i4];
    float inv = 1.0f / (float)(degw[m] + degw[16384 + m]);
    float4 o;
    o.x = (p0.x + p1.x) * inv + zz.x;
    o.y = (p0.y + p1.y) * inv + zz.y;
    o.z = (p0.z + p1.z) * inv + zz.z;
    o.w = (p0.w + p1.w) * inv + zz.w;
    ((float4*)out)[i4] = o;
}

extern "C" void kernel_launch(void* const* d_in, const int* in_sizes, int n_in,
                              void* d_out, int out_size, void* d_ws, size_t ws_size,
                              hipStream_t stream) {
    const float* x      = (const float*)d_in[0];
    const int*   adj    = (const int*)d_in[1];
    const float* weight = (const float*)d_in[2];
    const float* bias   = (const float*)d_in[3];
    float* out = (float*)d_out;

    // ws: WT 256KB | yTt 8MB | z 16MB | part 32MB | degw 128KB
    char* wsb = (char*)d_ws;
    uint16_t* wt    = (uint16_t*)(wsb);
    uint16_t* yTt   = (uint16_t*)(wsb + 262144);
    float*    z     = (float*)(wsb + 262144 + 8388608);
    float*    partb = (float*)(wsb + 262144 + 8388608 + 16777216);
    int*      degw  = (int*)(wsb + 262144 + 8388608 + 16777216 + 33554432);

    k_transpose_w<<<512, 256, 0, stream>>>(weight, wt);
    k_small_gemm<<<dim3(4, 128), 256, 0, stream>>>(x, wt, bias, yTt, z);
    k_big_gemm<<<dim3(256, 2), 512, 0, stream>>>(adj, yTt, partb, degw);
    k_reduce<<<4096, 256, 0, stream>>>(partb, degw, z, out);
}